// Round 3
// baseline (2749.474 us; speedup 1.0000x reference)
//
#include <hip/hip_runtime.h>
#include <stdint.h>

// ---------------------------------------------------------------------------
// MarketScoringUnit: LSTM(B=128,T=512,H=512) + attention + (mu, sigma) head.
// Round 13: R12 minus the U1s LDS staging. The attn-chain B-fragments
// (U1a rows for this wave's 64 n-values) are loop-invariant -> held in
// registers (Ureg[16], 64 VGPRs) instead of re-read from LDS every step
// (R12's pitch-520 layout was an 8-way bank conflict on every ds_read_b128:
// SQ_LDS_BANK_CONFLICT 1.57e7 -> 2.41e7, ~+550 cy/step). LDS kept at 86016
// via padding so every mega WG still gets a full CU (isolation preserved).
// ---------------------------------------------------------------------------

using short8  = __attribute__((ext_vector_type(8))) short;   // 8 bf16 (4 VGPRs)
using short4v = __attribute__((ext_vector_type(4))) short;
using floatx4 = __attribute__((ext_vector_type(4))) float;

#define MFMA16(a, b, c) __builtin_amdgcn_mfma_f32_16x16x32_bf16((a), (b), (c), 0, 0, 0)

__device__ __forceinline__ unsigned short f2b(float f) {
    unsigned u = __float_as_uint(f);
    u += 0x7FFFu + ((u >> 16) & 1u);           // RNE
    return (unsigned short)(u >> 16);
}
__device__ __forceinline__ float b2f(unsigned short h) {
    return __uint_as_float(((unsigned)h) << 16);
}
__device__ __forceinline__ float sigm(float x) { return 1.0f / (1.0f + __expf(-x)); }
__device__ __forceinline__ float tanh_(float x) { return 1.0f - 2.0f / (__expf(2.0f * x) + 1.0f); }

// ---------------------------------------------------------------------------
// prep: fp32 -> bf16 conversions, U1 split into U1a/U1b, bias = b_ih + b_hh
// ---------------------------------------------------------------------------
__global__ __launch_bounds__(256) void prep(
    const float* __restrict__ x, const float* __restrict__ Wih, const float* __restrict__ Whh,
    const float* __restrict__ bih, const float* __restrict__ bhh,
    const float* __restrict__ U1, const float* __restrict__ U2,
    unsigned short* __restrict__ x_bf, unsigned short* __restrict__ Wih_bf,
    unsigned short* __restrict__ Whh_bf, unsigned short* __restrict__ U1a,
    unsigned short* __restrict__ U1b, unsigned short* __restrict__ U2b,
    float* __restrict__ bias)
{
    const long long NX4 = 33554432LL / 4;  // x as float4
    const long long NREST = 1048576LL + 1048576LL + 524288LL + 262144LL + 2048LL;
    const long long total = NX4 + NREST;
    for (long long u = (long long)blockIdx.x * 256 + threadIdx.x; u < total;
         u += (long long)gridDim.x * 256) {
        if (u < NX4) {
            float4 v = ((const float4*)x)[u];
            short4v o;
            o[0] = (short)f2b(v.x); o[1] = (short)f2b(v.y);
            o[2] = (short)f2b(v.z); o[3] = (short)f2b(v.w);
            *(short4v*)&x_bf[u * 4] = o;
        } else {
            long long i = u - NX4;
            if (i < 1048576) { Wih_bf[i] = f2b(Wih[i]); continue; }
            i -= 1048576;
            if (i < 1048576) { Whh_bf[i] = f2b(Whh[i]); continue; }
            i -= 1048576;
            if (i < 524288) {
                int row = (int)(i >> 10), col = (int)(i & 1023);
                if (col < 512) U1a[row * 512 + col] = f2b(U1[i]);
                else           U1b[row * 512 + (col - 512)] = f2b(U1[i]);
                continue;
            }
            i -= 524288;
            if (i < 262144) { U2b[i] = f2b(U2[i]); continue; }
            i -= 262144;
            bias[i] = bih[i] + bhh[i];
        }
    }
}

// ---------------------------------------------------------------------------
// gemm_core: C[m][n] = sum_k A[m][k]*B[n][k] (+bias[n]); bf16, fp32 acc.
// 128x128 tile, BK=64, 4 waves of 64x64. mode==1: scatter into xg layout
// [t][jg][b][c], c = gate*16+(n&15), jg=(n>>4)&31, gate=n>>9.
// ---------------------------------------------------------------------------
__device__ __forceinline__ void gemm_core(
    const unsigned short* __restrict__ A, long long lda,
    const unsigned short* __restrict__ Bm, long long ldb,
    unsigned short* __restrict__ C, long long ldc,
    const float* __restrict__ bias, int mode,
    int m0, int n0, int tid, unsigned short* sbuf)
{
    unsigned short* At = sbuf;
    unsigned short* Bt = sbuf + 128 * 72;
    unsigned short* Ct = sbuf;  // alias, used after final sync

    const int wv = tid >> 6, lane = tid & 63, l15 = lane & 15, q = lane >> 4;
    const int wm = wv & 1, wn = wv >> 1;

    floatx4 acc[4][4];
    for (int i = 0; i < 4; i++)
        for (int j = 0; j < 4; j++) acc[i][j] = (floatx4){0.f, 0.f, 0.f, 0.f};

    for (int k0 = 0; k0 < 512; k0 += 64) {
        for (int p = 0; p < 4; p++) {
            int idx = tid + p * 256;
            int row = idx >> 3, ch = idx & 7;
            *(short8*)&At[row * 72 + ch * 8] =
                *(const short8*)&A[(long long)(m0 + row) * lda + k0 + ch * 8];
            *(short8*)&Bt[row * 72 + ch * 8] =
                *(const short8*)&Bm[(long long)(n0 + row) * ldb + k0 + ch * 8];
        }
        __syncthreads();
        for (int ks = 0; ks < 64; ks += 32) {
            short8 af[4], bfv[4];
            for (int mi = 0; mi < 4; mi++)
                af[mi] = *(const short8*)&At[(wm * 64 + mi * 16 + l15) * 72 + ks + q * 8];
            for (int ni = 0; ni < 4; ni++)
                bfv[ni] = *(const short8*)&Bt[(wn * 64 + ni * 16 + l15) * 72 + ks + q * 8];
            for (int mi = 0; mi < 4; mi++)
                for (int ni = 0; ni < 4; ni++)
                    acc[mi][ni] = MFMA16(af[mi], bfv[ni], acc[mi][ni]);
        }
        __syncthreads();
    }

    float bv[4];
    for (int ni = 0; ni < 4; ni++)
        bv[ni] = bias ? bias[n0 + wn * 64 + ni * 16 + l15] : 0.0f;

    for (int mi = 0; mi < 4; mi++)
        for (int ni = 0; ni < 4; ni++)
            for (int r = 0; r < 4; r++)
                Ct[(wm * 64 + mi * 16 + q * 4 + r) * 128 + wn * 64 + ni * 16 + l15] =
                    f2b(acc[mi][ni][r] + bv[ni]);
    __syncthreads();

    const int tt0 = m0 & 511, bglob = m0 >> 9;
    for (int p = 0; p < 8; p++) {
        int idx = tid + p * 256;
        int row = idx >> 4, ch = idx & 15;
        if (mode) {
            int n = n0 + ch * 8;
            int gate = n >> 9, jg = (n >> 4) & 31, c0 = gate * 16 + (n & 15);
            long long dst = (((long long)(tt0 + row) * 32 + jg) * 128 + bglob) * 64 + c0;
            *(short8*)&C[dst] = *(const short8*)&Ct[row * 128 + ch * 8];
        } else {
            *(short8*)&C[(long long)(m0 + row) * ldc + n0 + ch * 8] =
                *(const short8*)&Ct[row * 128 + ch * 8];
        }
    }
}

__global__ __launch_bounds__(256) void gemm_bt(
    const unsigned short* __restrict__ A, long long lda,
    const unsigned short* __restrict__ Bm, long long ldb,
    unsigned short* __restrict__ C, long long ldc,
    const float* __restrict__ bias, int mode, int mmul)
{
    __shared__ __align__(16) unsigned short sbuf[2 * 128 * 72];
    gemm_core(A, lda, Bm, ldb, C, ldc, bias, mode,
              blockIdx.x * mmul, blockIdx.y * 128, threadIdx.x, sbuf);
}

// ---------------------------------------------------------------------------
// mega: blockIdx < 64 -> lstm recurrence (R7 verbatim) + in-WG attn chain:
//   each step t the WG holds h_{t-1} (16 batches x 512 hid) in LDS -- the
//   exact A-matrix for a[b,t-1,n] = h@U1a^T on n in [jgb*64, jgb*64+64).
//   One extra MFMA per kk reusing af; B-fragments (Ureg) are loop-invariant
//   and live in registers. fp32 result stored into the consumed xg[t-1]
//   slot (safe: ring tag t-1 proves all consumers are past t-1 via the
//   xg-load -> MFMA -> ring-publish data dependency). Tail step: a[511].
// blockIdx >= 64 -> xg GEMM for t in [128, 512) (6144 WGs, R10 verbatim).
// LDS padded to 86016 => 1 WG/CU: lstm WGs isolated on their own CUs
// regardless of the final VGPR count.
// ---------------------------------------------------------------------------
#define GEMM_WGS 6144
__global__ __launch_bounds__(256, 1) void mega(
    const unsigned short* __restrict__ xg,   // [t][jg32][b][c]  c = gate*16+hl
    const unsigned short* __restrict__ Whh,  // (2048, 512) bf16
    unsigned short* __restrict__ h_all,      // [b][t][h]  (128, 512, 512)
    unsigned int* __restrict__ ring,         // [2][128][512] tagged words
    const unsigned short* __restrict__ x_bf,
    const unsigned short* __restrict__ Wih_bf,
    const float* __restrict__ bias,
    unsigned short* __restrict__ xg_out,
    int* __restrict__ done,
    const unsigned short* __restrict__ U1a)
{
    __shared__ __align__(16) char smem[86016];   // 36864 used; pad -> 1 WG/CU

    const int tid = threadIdx.x;

    if (blockIdx.x >= 64) {
        // ---------------- xg GEMM role: t in [128,512) ----------------
        int g = blockIdx.x - 64;
        int b = g & 127;
        int r = g >> 7;                  // 0..47
        int ti = 1 + (r % 3);            // 1..3
        int n = r / 3;                   // 0..15
        gemm_core(x_bf, 512, Wih_bf, 512, xg_out, 2048, bias, 1,
                  b * 512 + ti * 128, n * 128, tid, (unsigned short*)smem);
        __syncthreads();                 // all waves' stores drained
        if (tid == 0)
            __hip_atomic_fetch_add(done, 1, __ATOMIC_RELEASE,
                                   __HIP_MEMORY_SCOPE_AGENT);
        return;
    }

    // ---------------- lstm role (R7 verbatim + attn chain) ----------------
    unsigned int (*At)[16 * 264] = (unsigned int (*)[16 * 264])smem;

    const int wv = tid >> 6, lane = tid & 63, l15 = lane & 15, q = lane >> 4;
    const int bg = blockIdx.x >> 3, jgb = blockIdx.x & 7;
    const int b0 = bg * 16;
    const int jg32 = jgb * 4 + wv;            // 16-hid group of this wave
    const int hid = jg32 * 16 + l15;          // this lane's hidden index

    // W_hh B-frags: Wreg[ct][kk], row = ct*512 + hid, k = kk*32 + q*8
    short8 Wreg[4][16];
    #pragma unroll
    for (int ct = 0; ct < 4; ct++)
        #pragma unroll
        for (int kk = 0; kk < 16; kk++)
            Wreg[ct][kk] = *(const short8*)
                &Whh[(long long)(ct * 512 + hid) * 512 + kk * 32 + q * 8];

    // attn-chain B-frags (loop-invariant): row n = jgb*64 + wv*16 + l15
    short8 Ureg[16];
    {
        const unsigned short* u1g =
            &U1a[(long long)(jgb * 64 + wv * 16 + l15) * 512 + q * 8];
        #pragma unroll
        for (int kk = 0; kk < 16; kk++)
            Ureg[kk] = *(const short8*)&u1g[kk * 32];
    }

    float cst[4] = {0.f, 0.f, 0.f, 0.f};

    // attn output mapping for this wave: n = jgb*64 + wv*16 + l15
    const int jgp = jgb * 2 + (wv >> 1);      // n >> 5
    const int c0a = (wv & 1) * 16 + l15;      // n & 31

    for (int t = 0; t < 512; t++) {
        // one-time guard: xg[t>=128] is produced by the gemm role
        if (t == 128) {
            if (tid == 0) {
                while (__hip_atomic_load(done, __ATOMIC_ACQUIRE,
                                         __HIP_MEMORY_SCOPE_AGENT) < GEMM_WGS)
                    __builtin_amdgcn_s_sleep(8);
            }
            __syncthreads();
        }
        // ---- prefetch xg: acc-init values, 16 scalar loads (pre-poll) ----
        const long long xbase = ((long long)(t * 32 + jg32) * 128 + b0) * 64;
        floatx4 acc[4];
        #pragma unroll
        for (int ct = 0; ct < 4; ct++)
            #pragma unroll
            for (int r = 0; r < 4; r++)
                acc[ct][r] = b2f(xg[xbase + (q * 4 + r) * 64 + ct * 16 + l15]);

        floatx4 acc_a = (floatx4){0.f, 0.f, 0.f, 0.f};

        if (t > 0) {
            const unsigned want = (unsigned)(t - 1);
            const int sl = (t - 1) & 1;
            unsigned long long* rb = (unsigned long long*)
                (ring + sl * 65536 + b0 * 512);
            unsigned long long w[16];
            #pragma unroll
            for (int i = 0; i < 16; i++)
                w[i] = __hip_atomic_load(&rb[tid + i * 256], __ATOMIC_RELAXED,
                                         __HIP_MEMORY_SCOPE_AGENT);
            while (true) {
                unsigned bad = 0;
                #pragma unroll
                for (int i = 0; i < 16; i++) {
                    unsigned lo = (unsigned)(w[i] >> 16) & 0xFFFFu;
                    unsigned hi = (unsigned)(w[i] >> 48);
                    bad |= (lo ^ want) | (hi ^ want);
                }
                if (!bad) break;
                #pragma unroll
                for (int i = 0; i < 16; i++) {
                    unsigned lo = (unsigned)(w[i] >> 16) & 0xFFFFu;
                    unsigned hi = (unsigned)(w[i] >> 48);
                    if ((lo ^ want) | (hi ^ want))
                        w[i] = __hip_atomic_load(&rb[tid + i * 256], __ATOMIC_RELAXED,
                                                 __HIP_MEMORY_SCOPE_AGENT);
                }
            }
            // strip tags, pack two bf16 per LDS word
            unsigned int* dst = &At[sl][0];
            #pragma unroll
            for (int i = 0; i < 16; i++) {
                int idx = tid + i * 256;
                int row = idx >> 8, k = idx & 255;
                dst[row * 264 + k] =
                    (unsigned)(w[i] & 0xFFFFu) | ((unsigned)(w[i] >> 32) << 16);
            }
            __syncthreads();
            // MFMA: A = h tile (batch l15, K), B = Wreg; 4 gate chains + the
            // attn chain (acc_a, B = Ureg) reusing the same af.
            const unsigned int* ap = &At[sl][l15 * 264 + q * 4];
            #pragma unroll
            for (int kk = 0; kk < 16; kk++) {
                short8 af = *(const short8*)(ap + kk * 16);
                acc[0] = MFMA16(af, Wreg[0][kk], acc[0]);
                acc[1] = MFMA16(af, Wreg[1][kk], acc[1]);
                acc[2] = MFMA16(af, Wreg[2][kk], acc[2]);
                acc[3] = MFMA16(af, Wreg[3][kk], acc[3]);
                acc_a = MFMA16(af, Ureg[kk], acc_a);
            }
        }
        // ---- pointwise: gates are in-lane (acc[0..3] = i,f,g,o) ----
        unsigned short hbv[4];
        #pragma unroll
        for (int r = 0; r < 4; r++) {
            float ig = sigm(acc[0][r]);
            float fg = sigm(acc[1][r]);
            float gv = tanh_(acc[2][r]);
            float og = sigm(acc[3][r]);
            cst[r] = fg * cst[r] + ig * gv;
            hbv[r] = f2b(og * tanh_(cst[r]));
        }
        // publish: ring first (latency-critical), then h_all
        #pragma unroll
        for (int r = 0; r < 4; r++) {
            const int b = b0 + q * 4 + r;
            __hip_atomic_store(&ring[(t & 1) * 65536 + b * 512 + hid],
                               ((unsigned)t << 16) | hbv[r], __ATOMIC_RELAXED,
                               __HIP_MEMORY_SCOPE_AGENT);
        }
        #pragma unroll
        for (int r = 0; r < 4; r++) {
            const int b = b0 + q * 4 + r;
            h_all[(long long)b * 262144 + (long long)t * 512 + hid] = hbv[r];
        }
        // ---- attn store: a[t-1, n] (fp32, into consumed xg slot) ----
        if (t > 0) {
            #pragma unroll
            for (int r = 0; r < 4; r++) {
                const int b = b0 + q * 4 + r;
                float* slot = (float*)&xg_out[(((long long)(t - 1) * 32 + jgp) * 128 + b) * 64];
                slot[c0a] = acc_a[r];
            }
        }
    }

    // ---- tail: a[511] from h_511 (ring slot 1, tag 511) ----
    {
        const unsigned want = 511u;
        const int sl = 1;
        unsigned long long* rb = (unsigned long long*)
            (ring + sl * 65536 + b0 * 512);
        unsigned long long w[16];
        #pragma unroll
        for (int i = 0; i < 16; i++)
            w[i] = __hip_atomic_load(&rb[tid + i * 256], __ATOMIC_RELAXED,
                                     __HIP_MEMORY_SCOPE_AGENT);
        while (true) {
            unsigned bad = 0;
            #pragma unroll
            for (int i = 0; i < 16; i++) {
                unsigned lo = (unsigned)(w[i] >> 16) & 0xFFFFu;
                unsigned hi = (unsigned)(w[i] >> 48);
                bad |= (lo ^ want) | (hi ^ want);
            }
            if (!bad) break;
            #pragma unroll
            for (int i = 0; i < 16; i++) {
                unsigned lo = (unsigned)(w[i] >> 16) & 0xFFFFu;
                unsigned hi = (unsigned)(w[i] >> 48);
                if ((lo ^ want) | (hi ^ want))
                    w[i] = __hip_atomic_load(&rb[tid + i * 256], __ATOMIC_RELAXED,
                                             __HIP_MEMORY_SCOPE_AGENT);
            }
        }
        unsigned int* dst = &At[sl][0];
        #pragma unroll
        for (int i = 0; i < 16; i++) {
            int idx = tid + i * 256;
            int row = idx >> 8, k = idx & 255;
            dst[row * 264 + k] =
                (unsigned)(w[i] & 0xFFFFu) | ((unsigned)(w[i] >> 32) << 16);
        }
        __syncthreads();
        const unsigned int* ap = &At[sl][l15 * 264 + q * 4];
        floatx4 acc_a = (floatx4){0.f, 0.f, 0.f, 0.f};
        #pragma unroll
        for (int kk = 0; kk < 16; kk++) {
            short8 af = *(const short8*)(ap + kk * 16);
            acc_a = MFMA16(af, Ureg[kk], acc_a);
        }
        #pragma unroll
        for (int r = 0; r < 4; r++) {
            const int b = b0 + q * 4 + r;
            float* slot = (float*)&xg_out[(((long long)511 * 32 + jgp) * 128 + b) * 64];
            slot[c0a] = acc_a[r];
        }
    }
}

// ---------------------------------------------------------------------------
// attn_e2: e[b,t] = Ve . tanh(a[t,n,b] + (x@U2^T)[b,t,n] + u1b[b,n]).
// a (= h@U1a^T, fp32) comes from the consumed-xg slots written by mega.
// 32 t per WG; only the U2 GEMM is computed here (16 k-iterations).
// ---------------------------------------------------------------------------
__global__ __launch_bounds__(256) void attn_e2(
    const unsigned short* __restrict__ a_xg,
    const unsigned short* __restrict__ x_bf,
    const unsigned short* __restrict__ U2b,
    const unsigned short* __restrict__ u1bv,  // bf16 (128,512)
    const float* __restrict__ Ve,
    float* __restrict__ e)
{
    __shared__ __align__(16) unsigned short Bt[512 * 40];
    __shared__ __align__(16) unsigned short At[32 * 40];
    __shared__ float ered[4][32];

    const int tid = threadIdx.x;
    const int wv = tid >> 6, lane = tid & 63, l15 = lane & 15, q = lane >> 4;
    const int b = blockIdx.x >> 4, t0 = (blockIdx.x & 15) * 32;

    floatx4 acc[2][8];
    for (int mi = 0; mi < 2; mi++)
        for (int ni = 0; ni < 8; ni++) acc[mi][ni] = (floatx4){0.f, 0.f, 0.f, 0.f};

    for (int it = 0; it < 16; it++) {
        const int kk = it * 32;
        __syncthreads();
        for (int idx = tid; idx < 2048; idx += 256) {
            int row = idx >> 2, ch = idx & 3;
            *(short8*)&Bt[row * 40 + ch * 8] =
                *(const short8*)&U2b[(long long)row * 512 + kk + ch * 8];
        }
        if (tid < 128) {
            int row = tid >> 2, ch = tid & 3;
            *(short8*)&At[row * 40 + ch * 8] =
                *(const short8*)&x_bf[(long long)(b * 512 + t0 + row) * 512 + kk + ch * 8];
        }
        __syncthreads();
        short8 af[2];
        for (int mi = 0; mi < 2; mi++)
            af[mi] = *(const short8*)&At[(mi * 16 + l15) * 40 + q * 8];
        for (int ni = 0; ni < 8; ni++) {
            short8 bfv = *(const short8*)&Bt[(wv * 128 + ni * 16 + l15) * 40 + q * 8];
            acc[0][ni] = MFMA16(af[0], bfv, acc[0][ni]);
            acc[1][ni] = MFMA16(af[1], bfv, acc[1][ni]);
        }
    }

    float s[2][4] = {{0.f, 0.f, 0.f, 0.f}, {0.f, 0.f, 0.f, 0.f}};
    for (int ni = 0; ni < 8; ni++) {
        const int n = wv * 128 + ni * 16 + l15;
        const float ub = b2f(u1bv[b * 512 + n]);
        const float vev = Ve[n];
        const int jgp = n >> 5, c0 = n & 31;
        for (int mi = 0; mi < 2; mi++) {
            #pragma unroll
            for (int r = 0; r < 4; r++) {
                const int t = t0 + mi * 16 + q * 4 + r;
                float av = ((const float*)&a_xg[(((long long)t * 32 + jgp) * 128 + b) * 64])[c0];
                s[mi][r] += vev * tanh_(acc[mi][ni][r] + av + ub);
            }
        }
    }
    for (int off = 1; off <= 8; off <<= 1)
        for (int mi = 0; mi < 2; mi++)
            for (int r = 0; r < 4; r++) s[mi][r] += __shfl_xor(s[mi][r], off);
    if (l15 == 0)
        for (int mi = 0; mi < 2; mi++)
            for (int r = 0; r < 4; r++) ered[wv][mi * 16 + q * 4 + r] = s[mi][r];
    __syncthreads();
    if (tid < 32)
        e[(long long)b * 512 + t0 + tid] =
            ered[0][tid] + ered[1][tid] + ered[2][tid] + ered[3][tid];
}

// ---------------------------------------------------------------------------
// attn_out: softmax over T, context = alpha.h, head -> mu, sigma. 1 WG per b.
// h loads packed (uint = 2 bf16), thread owns hid pair (2*tid, 2*tid+1).
// ---------------------------------------------------------------------------
__global__ __launch_bounds__(256) void attn_out(
    const float* __restrict__ e, const unsigned short* __restrict__ h_all,
    const float* __restrict__ Wout, const float* __restrict__ bout,
    float* __restrict__ outp)
{
    __shared__ float sm[512];
    __shared__ float red[8];
    const int b = blockIdx.x, tid = threadIdx.x;
    const int wv = tid >> 6, lane = tid & 63;

    float e0 = e[b * 512 + tid], e1 = e[b * 512 + 256 + tid];
    float mx = fmaxf(e0, e1);
    for (int off = 32; off; off >>= 1) mx = fmaxf(mx, __shfl_xor(mx, off));
    if (lane == 0) red[wv] = mx;
    __syncthreads();
    mx = fmaxf(fmaxf(red[0], red[1]), fmaxf(red[2], red[3]));

    float s0 = __expf(e0 - mx), s1 = __expf(e1 - mx);
    sm[tid] = s0; sm[256 + tid] = s1;
    float ss = s0 + s1;
    for (int off = 32; off; off >>= 1) ss += __shfl_xor(ss, off);
    if (lane == 0) red[4 + wv] = ss;
    __syncthreads();
    float inv = 1.0f / (red[4] + red[5] + red[6] + red[7]);

    const unsigned int* hp = (const unsigned int*)(h_all + (long long)b * 262144);
    float a0 = 0.f, a1 = 0.f;
    for (int t = 0; t < 512; t += 4) {
        #pragma unroll
        for (int j = 0; j < 4; j++) {
            float al = sm[t + j];
            unsigned v = hp[(t + j) * 256 + tid];
            a0 += al * b2f((unsigned short)(v & 0xFFFFu));
            a1 += al * b2f((unsigned short)(v >> 16));
        }
    }
    a0 *= inv; a1 *= inv;

    float q0 = a0 * Wout[2 * tid] + a1 * Wout[2 * tid + 1];
    float q1 = a0 * Wout[512 + 2 * tid] + a1 * Wout[512 + 2 * tid + 1];
    for (int off = 32; off; off >>= 1) { q0 += __shfl_xor(q0, off); q1 += __shfl_xor(q1, off); }
    __syncthreads();  // red reuse
    if (lane == 0) { red[wv] = q0; red[4 + wv] = q1; }
    __syncthreads();
    if (tid == 0) {
        float P0 = red[0] + red[1] + red[2] + red[3] + bout[0];
        float P1 = red[4] + red[5] + red[6] + red[7] + bout[1];
        outp[b] = P0;
        float sp = (P1 > 15.0f) ? P1 : log1pf(__expf(P1));
        outp[128 + b] = sp + 1e-5f;
    }
}

// ---------------------------------------------------------------------------
extern "C" void kernel_launch(void* const* d_in, const int* in_sizes, int n_in,
                              void* d_out, int out_size, void* d_ws, size_t ws_size,
                              hipStream_t stream)
{
    const float* x    = (const float*)d_in[0];
    const float* Wih  = (const float*)d_in[1];
    const float* Whh  = (const float*)d_in[2];
    const float* bih  = (const float*)d_in[3];
    const float* bhh  = (const float*)d_in[4];
    const float* Ve   = (const float*)d_in[5];
    const float* U1   = (const float*)d_in[6];
    const float* U2   = (const float*)d_in[7];
    const float* Wout = (const float*)d_in[8];
    const float* bout = (const float*)d_in[9];
    float* out = (float*)d_out;

    char* ws = (char*)d_ws;
    size_t off = 0;
    auto alloc = [&](size_t bytes) -> void* {
        void* p = ws + off;
        off += (bytes + 255) & ~(size_t)255;
        return p;
    };
    unsigned short* x_bf   = (unsigned short*)alloc(33554432ull * 2);
    unsigned short* Wih_bf = (unsigned short*)alloc(1048576ull * 2);
    unsigned short* Whh_bf = (unsigned short*)alloc(1048576ull * 2);
    unsigned short* U1a    = (unsigned short*)alloc(262144ull * 2);
    unsigned short* U1b    = (unsigned short*)alloc(262144ull * 2);
    unsigned short* U2b    = (unsigned short*)alloc(262144ull * 2);
    float*          bias   = (float*)alloc(2048ull * 4);
    unsigned short* xg     = (unsigned short*)alloc(134217728ull * 2);
    unsigned short* h_all  = (unsigned short*)alloc(33554432ull * 2);
    unsigned short* u1bv   = (unsigned short*)alloc(65536ull * 2);
    float*          e      = (float*)alloc(65536ull * 4);
    unsigned int*   ring   = (unsigned int*)alloc(131072ull * 4);  // 2x128x512 tagged
    int*            done   = (int*)alloc(256ull);
    if (off > ws_size) return;  // workspace too small: fail safe (no corruption)

    hipMemsetAsync(done, 0, 4, stream);
    prep<<<4096, 256, 0, stream>>>(x, Wih, Whh, bih, bhh, U1, U2,
                                   x_bf, Wih_bf, Whh_bf, U1a, U1b, U2b, bias);
    // xg for t<128 only (ti=0): m0 = b*512, 2048 WGs
    gemm_bt<<<dim3(128, 16), 256, 0, stream>>>(x_bf, 512, Wih_bf, 512,
                                               xg, 2048, bias, 1, 512);
    // mega: 64 lstm WGs (+ in-WG attn h@U1a chain) + 6144 gemm WGs
    mega<<<64 + GEMM_WGS, 256, 0, stream>>>(xg, Whh_bf, h_all, ring,
                                            x_bf, Wih_bf, bias, xg, done, U1a);
    // u1b = h_last @ U1b^T
    gemm_bt<<<dim3(1, 4), 256, 0, stream>>>(h_all + 511 * 512, 262144, U1b, 512,
                                            u1bv, 512, nullptr, 0, 128);
    attn_e2<<<2048, 256, 0, stream>>>(xg, x_bf, U2b, u1bv, Ve, e);
    attn_out<<<128, 256, 0, stream>>>(e, h_all, Wout, bout, out);
}

// Round 4
// 2561.694 us; speedup vs baseline: 1.0733x; 1.0733x over previous
//
#include <hip/hip_runtime.h>
#include <stdint.h>

// ---------------------------------------------------------------------------
// MarketScoringUnit: LSTM(B=128,T=512,H=512) + attention + (mu, sigma) head.
// Round 14: lstm role reverted to R10 verbatim (no attn chain, no micro-opts;
// only the publish is atomic-packed + a progress word every 16 steps).
// R11's shadow helpers (a = h@U1a^T + x@U2^T into consumed xg slots) are
// re-added, but now under the 86016-LDS 1-WG/CU isolation that R13 proved:
// helpers/gemm can never co-reside with lstm WGs. Helper Bt pitch 40
// (2-way bank = free; R11's pitch 32 was 8-way). Progress words spread to
// one cache line per WG. attn_e2 deleted; attn_out does Ve.tanh(a+u1b).
// ---------------------------------------------------------------------------

using short8  = __attribute__((ext_vector_type(8))) short;   // 8 bf16 (4 VGPRs)
using short4v = __attribute__((ext_vector_type(4))) short;
using floatx4 = __attribute__((ext_vector_type(4))) float;

#define MFMA16(a, b, c) __builtin_amdgcn_mfma_f32_16x16x32_bf16((a), (b), (c), 0, 0, 0)

__device__ __forceinline__ unsigned short f2b(float f) {
    unsigned u = __float_as_uint(f);
    u += 0x7FFFu + ((u >> 16) & 1u);           // RNE
    return (unsigned short)(u >> 16);
}
__device__ __forceinline__ float b2f(unsigned short h) {
    return __uint_as_float(((unsigned)h) << 16);
}
__device__ __forceinline__ float sigm(float x) { return 1.0f / (1.0f + __expf(-x)); }
__device__ __forceinline__ float tanh_(float x) { return 1.0f - 2.0f / (__expf(2.0f * x) + 1.0f); }

// ---------------------------------------------------------------------------
// prep: fp32 -> bf16 conversions, U1 split into U1a/U1b, bias = b_ih + b_hh
// ---------------------------------------------------------------------------
__global__ __launch_bounds__(256) void prep(
    const float* __restrict__ x, const float* __restrict__ Wih, const float* __restrict__ Whh,
    const float* __restrict__ bih, const float* __restrict__ bhh,
    const float* __restrict__ U1, const float* __restrict__ U2,
    unsigned short* __restrict__ x_bf, unsigned short* __restrict__ Wih_bf,
    unsigned short* __restrict__ Whh_bf, unsigned short* __restrict__ U1a,
    unsigned short* __restrict__ U1b, unsigned short* __restrict__ U2b,
    float* __restrict__ bias)
{
    const long long NX4 = 33554432LL / 4;  // x as float4
    const long long NREST = 1048576LL + 1048576LL + 524288LL + 262144LL + 2048LL;
    const long long total = NX4 + NREST;
    for (long long u = (long long)blockIdx.x * 256 + threadIdx.x; u < total;
         u += (long long)gridDim.x * 256) {
        if (u < NX4) {
            float4 v = ((const float4*)x)[u];
            short4v o;
            o[0] = (short)f2b(v.x); o[1] = (short)f2b(v.y);
            o[2] = (short)f2b(v.z); o[3] = (short)f2b(v.w);
            *(short4v*)&x_bf[u * 4] = o;
        } else {
            long long i = u - NX4;
            if (i < 1048576) { Wih_bf[i] = f2b(Wih[i]); continue; }
            i -= 1048576;
            if (i < 1048576) { Whh_bf[i] = f2b(Whh[i]); continue; }
            i -= 1048576;
            if (i < 524288) {
                int row = (int)(i >> 10), col = (int)(i & 1023);
                if (col < 512) U1a[row * 512 + col] = f2b(U1[i]);
                else           U1b[row * 512 + (col - 512)] = f2b(U1[i]);
                continue;
            }
            i -= 524288;
            if (i < 262144) { U2b[i] = f2b(U2[i]); continue; }
            i -= 262144;
            bias[i] = bih[i] + bhh[i];
        }
    }
}

// ---------------------------------------------------------------------------
// gemm_core: C[m][n] = sum_k A[m][k]*B[n][k] (+bias[n]); bf16, fp32 acc.
// 128x128 tile, BK=64, 4 waves of 64x64. mode==1: scatter into xg layout
// [t][jg][b][c], c = gate*16+(n&15), jg=(n>>4)&31, gate=n>>9.
// ---------------------------------------------------------------------------
__device__ __forceinline__ void gemm_core(
    const unsigned short* __restrict__ A, long long lda,
    const unsigned short* __restrict__ Bm, long long ldb,
    unsigned short* __restrict__ C, long long ldc,
    const float* __restrict__ bias, int mode,
    int m0, int n0, int tid, unsigned short* sbuf)
{
    unsigned short* At = sbuf;
    unsigned short* Bt = sbuf + 128 * 72;
    unsigned short* Ct = sbuf;  // alias, used after final sync

    const int wv = tid >> 6, lane = tid & 63, l15 = lane & 15, q = lane >> 4;
    const int wm = wv & 1, wn = wv >> 1;

    floatx4 acc[4][4];
    for (int i = 0; i < 4; i++)
        for (int j = 0; j < 4; j++) acc[i][j] = (floatx4){0.f, 0.f, 0.f, 0.f};

    for (int k0 = 0; k0 < 512; k0 += 64) {
        for (int p = 0; p < 4; p++) {
            int idx = tid + p * 256;
            int row = idx >> 3, ch = idx & 7;
            *(short8*)&At[row * 72 + ch * 8] =
                *(const short8*)&A[(long long)(m0 + row) * lda + k0 + ch * 8];
            *(short8*)&Bt[row * 72 + ch * 8] =
                *(const short8*)&Bm[(long long)(n0 + row) * ldb + k0 + ch * 8];
        }
        __syncthreads();
        for (int ks = 0; ks < 64; ks += 32) {
            short8 af[4], bfv[4];
            for (int mi = 0; mi < 4; mi++)
                af[mi] = *(const short8*)&At[(wm * 64 + mi * 16 + l15) * 72 + ks + q * 8];
            for (int ni = 0; ni < 4; ni++)
                bfv[ni] = *(const short8*)&Bt[(wn * 64 + ni * 16 + l15) * 72 + ks + q * 8];
            for (int mi = 0; mi < 4; mi++)
                for (int ni = 0; ni < 4; ni++)
                    acc[mi][ni] = MFMA16(af[mi], bfv[ni], acc[mi][ni]);
        }
        __syncthreads();
    }

    float bv[4];
    for (int ni = 0; ni < 4; ni++)
        bv[ni] = bias ? bias[n0 + wn * 64 + ni * 16 + l15] : 0.0f;

    for (int mi = 0; mi < 4; mi++)
        for (int ni = 0; ni < 4; ni++)
            for (int r = 0; r < 4; r++)
                Ct[(wm * 64 + mi * 16 + q * 4 + r) * 128 + wn * 64 + ni * 16 + l15] =
                    f2b(acc[mi][ni][r] + bv[ni]);
    __syncthreads();

    const int tt0 = m0 & 511, bglob = m0 >> 9;
    for (int p = 0; p < 8; p++) {
        int idx = tid + p * 256;
        int row = idx >> 4, ch = idx & 15;
        if (mode) {
            int n = n0 + ch * 8;
            int gate = n >> 9, jg = (n >> 4) & 31, c0 = gate * 16 + (n & 15);
            long long dst = (((long long)(tt0 + row) * 32 + jg) * 128 + bglob) * 64 + c0;
            *(short8*)&C[dst] = *(const short8*)&Ct[row * 128 + ch * 8];
        } else {
            *(short8*)&C[(long long)(m0 + row) * ldc + n0 + ch * 8] =
                *(const short8*)&Ct[row * 128 + ch * 8];
        }
    }
}

__global__ __launch_bounds__(256) void gemm_bt(
    const unsigned short* __restrict__ A, long long lda,
    const unsigned short* __restrict__ Bm, long long ldb,
    unsigned short* __restrict__ C, long long ldc,
    const float* __restrict__ bias, int mode, int mmul)
{
    __shared__ __align__(16) unsigned short sbuf[2 * 128 * 72];
    gemm_core(A, lda, Bm, ldb, C, ldc, bias, mode,
              blockIdx.x * mmul, blockIdx.y * 128, threadIdx.x, sbuf);
}

// ---------------------------------------------------------------------------
// mega: blockIdx < 64            -> lstm recurrence (R10 verbatim; publish
//                                   via packed agent atomics + prog word)
//       64 <= blockIdx < 64+6144 -> xg GEMM for t in [128,512) (R10 verbatim)
//       blockIdx >= 64+6144      -> attn helper: a[b,t,n] = h@U1a^T + x@U2^T
//                                   (fp32, into consumed xg slots)
// LDS = 86016 for every role -> 1 WG/CU: helpers/gemm can never co-reside
// with lstm WGs (R11's regression cause). syncp[0] = gemm done counter;
// syncp[16 + wg*16] = per-lstm-WG progress (one cache line per WG).
// ---------------------------------------------------------------------------
#define GEMM_WGS 6144
#define ATTN_WGS 2048
__global__ __launch_bounds__(256, 1) void mega(
    const unsigned short* __restrict__ xg,   // [t][jg32][b][c]  c = gate*16+hl
    const unsigned short* __restrict__ Whh,  // (2048, 512) bf16
    unsigned short* __restrict__ h_all,      // [b][t][h]  (128, 512, 512)
    unsigned int* __restrict__ ring,         // [2][128][512] tagged words
    const unsigned short* __restrict__ x_bf,
    const unsigned short* __restrict__ Wih_bf,
    const float* __restrict__ bias,
    unsigned short* __restrict__ xg_out,
    int* __restrict__ syncp,
    const unsigned short* __restrict__ U1a,
    const unsigned short* __restrict__ U2b)
{
    __shared__ __align__(16) char smem[86016];   // forces 1 WG/CU for all roles

    const int tid = threadIdx.x;

    if (blockIdx.x >= 64 && blockIdx.x < 64 + GEMM_WGS) {
        // ---------------- xg GEMM role: t in [128,512) ----------------
        int g = blockIdx.x - 64;
        int b = g & 127;
        int r = g >> 7;                  // 0..47
        int ti = 1 + (r % 3);            // 1..3
        int n = r / 3;                   // 0..15
        gemm_core(x_bf, 512, Wih_bf, 512, xg_out, 2048, bias, 1,
                  b * 512 + ti * 128, n * 128, tid, (unsigned short*)smem);
        __syncthreads();                 // all waves' stores drained
        if (tid == 0)
            __hip_atomic_fetch_add(&syncp[0], 1, __ATOMIC_RELEASE,
                                   __HIP_MEMORY_SCOPE_AGENT);
        return;
    }

    if (blockIdx.x >= 64 + GEMM_WGS) {
        // ------------- attn helper role: a = h@U1a^T + x@U2^T -------------
        const int g = blockIdx.x - 64 - GEMM_WGS;
        const int tt = g >> 7;            // 0..15, ascending (dispatch order)
        const int b  = g & 127;
        const int t0 = tt * 32;
        const int bg = b >> 4;

        if (tid < 8) {
            while (__hip_atomic_load(&syncp[16 + (bg * 8 + tid) * 16],
                                     __ATOMIC_RELAXED,
                                     __HIP_MEMORY_SCOPE_AGENT) < t0 + 32)
                __builtin_amdgcn_s_sleep(8);
        }
        __syncthreads();

        unsigned short* Bt2 = (unsigned short*)smem;              // 512 x 40
        unsigned short* At2 = (unsigned short*)smem + 512 * 40;   // 32 x 40

        const int wv = tid >> 6, lane = tid & 63, l15 = lane & 15, q = lane >> 4;

        floatx4 acc[2][8];
        for (int mi = 0; mi < 2; mi++)
            for (int ni = 0; ni < 8; ni++) acc[mi][ni] = (floatx4){0.f, 0.f, 0.f, 0.f};

        for (int it = 0; it < 32; it++) {
            const int phase = it >> 4, kk = (it & 15) * 32;
            const unsigned short* Bsrc = phase ? U2b : U1a;
            __syncthreads();
            for (int idx = tid; idx < 2048; idx += 256) {
                int row = idx >> 2, ch = idx & 3;
                *(short8*)&Bt2[row * 40 + ch * 8] =
                    *(const short8*)&Bsrc[(long long)row * 512 + kk + ch * 8];
            }
            if (tid < 128) {
                int row = tid >> 2, ch = tid & 3;
                if (phase == 0) {
                    unsigned long long* p = (unsigned long long*)
                        &h_all[((long long)b * 512 + t0 + row) * 512 + kk + ch * 8];
                    unsigned long long lo = __hip_atomic_load(p, __ATOMIC_RELAXED,
                                                              __HIP_MEMORY_SCOPE_AGENT);
                    unsigned long long hi = __hip_atomic_load(p + 1, __ATOMIC_RELAXED,
                                                              __HIP_MEMORY_SCOPE_AGENT);
                    unsigned long long* d = (unsigned long long*)&At2[row * 40 + ch * 8];
                    d[0] = lo; d[1] = hi;
                } else {
                    *(short8*)&At2[row * 40 + ch * 8] =
                        *(const short8*)&x_bf[((long long)b * 512 + t0 + row) * 512 + kk + ch * 8];
                }
            }
            __syncthreads();
            short8 af0 = *(const short8*)&At2[(l15) * 40 + q * 8];
            short8 af1 = *(const short8*)&At2[(16 + l15) * 40 + q * 8];
            for (int ni = 0; ni < 8; ni++) {
                short8 bfv = *(const short8*)&Bt2[(wv * 128 + ni * 16 + l15) * 40 + q * 8];
                acc[0][ni] = MFMA16(af0, bfv, acc[0][ni]);
                acc[1][ni] = MFMA16(af1, bfv, acc[1][ni]);
            }
        }
        // write fp32 a[t,b,n] into the consumed xg slot (t*32+(n>>5))*128+b
        for (int mi = 0; mi < 2; mi++)
            for (int ni = 0; ni < 8; ni++) {
                const int n = wv * 128 + ni * 16 + l15;
                #pragma unroll
                for (int r = 0; r < 4; r++) {
                    const int t = t0 + mi * 16 + q * 4 + r;
                    float* slot = (float*)&xg_out[(((long long)t * 32 + (n >> 5)) * 128 + b) * 64];
                    slot[n & 31] = acc[mi][ni][r];
                }
            }
        return;
    }

    // ---------------- lstm role (R10 verbatim) ----------------
    unsigned int (*At)[16 * 264] = (unsigned int (*)[16 * 264])smem;

    const int wv = tid >> 6, lane = tid & 63, l15 = lane & 15, q = lane >> 4;
    const int bg = blockIdx.x >> 3, jgb = blockIdx.x & 7;
    const int b0 = bg * 16;
    const int jg32 = jgb * 4 + wv;            // 16-hid group of this wave
    const int hid = jg32 * 16 + l15;          // this lane's hidden index

    // W_hh B-frags: Wreg[ct][kk], row = ct*512 + hid, k = kk*32 + q*8
    short8 Wreg[4][16];
    #pragma unroll
    for (int ct = 0; ct < 4; ct++)
        #pragma unroll
        for (int kk = 0; kk < 16; kk++)
            Wreg[ct][kk] = *(const short8*)
                &Whh[(long long)(ct * 512 + hid) * 512 + kk * 32 + q * 8];

    float cst[4] = {0.f, 0.f, 0.f, 0.f};

    for (int t = 0; t < 512; t++) {
        // one-time guard: xg[t>=128] is produced by the gemm role
        if (t == 128) {
            if (tid == 0) {
                while (__hip_atomic_load(&syncp[0], __ATOMIC_ACQUIRE,
                                         __HIP_MEMORY_SCOPE_AGENT) < GEMM_WGS)
                    __builtin_amdgcn_s_sleep(8);
            }
            __syncthreads();
        }
        // ---- prefetch xg: acc-init values, 16 scalar loads (pre-poll) ----
        const long long xbase = ((long long)(t * 32 + jg32) * 128 + b0) * 64;
        floatx4 acc[4];
        #pragma unroll
        for (int ct = 0; ct < 4; ct++)
            #pragma unroll
            for (int r = 0; r < 4; r++)
                acc[ct][r] = b2f(xg[xbase + (q * 4 + r) * 64 + ct * 16 + l15]);

        if (t > 0) {
            const unsigned want = (unsigned)(t - 1);
            const int sl = (t - 1) & 1;
            unsigned long long* rb = (unsigned long long*)
                (ring + sl * 65536 + b0 * 512);
            unsigned long long w[16];
            #pragma unroll
            for (int i = 0; i < 16; i++)
                w[i] = __hip_atomic_load(&rb[tid + i * 256], __ATOMIC_RELAXED,
                                         __HIP_MEMORY_SCOPE_AGENT);
            while (true) {
                unsigned bad = 0;
                #pragma unroll
                for (int i = 0; i < 16; i++) {
                    unsigned lo = (unsigned)(w[i] >> 16) & 0xFFFFu;
                    unsigned hi = (unsigned)(w[i] >> 48);
                    bad |= (lo ^ want) | (hi ^ want);
                }
                if (!bad) break;
                #pragma unroll
                for (int i = 0; i < 16; i++) {
                    unsigned lo = (unsigned)(w[i] >> 16) & 0xFFFFu;
                    unsigned hi = (unsigned)(w[i] >> 48);
                    if ((lo ^ want) | (hi ^ want))
                        w[i] = __hip_atomic_load(&rb[tid + i * 256], __ATOMIC_RELAXED,
                                                 __HIP_MEMORY_SCOPE_AGENT);
                }
            }
            // strip tags, pack two bf16 per LDS word
            unsigned int* dst = &At[sl][0];
            #pragma unroll
            for (int i = 0; i < 16; i++) {
                int idx = tid + i * 256;
                int row = idx >> 8, k = idx & 255;
                dst[row * 264 + k] =
                    (unsigned)(w[i] & 0xFFFFu) | ((unsigned)(w[i] >> 32) << 16);
            }
            __syncthreads();
            // MFMA: A = h tile (batch l15, K), B = Wreg; 4 chains (one/gate)
            const unsigned int* ap = &At[sl][l15 * 264 + q * 4];
            #pragma unroll
            for (int kk = 0; kk < 16; kk++) {
                short8 af = *(const short8*)(ap + kk * 16);
                acc[0] = MFMA16(af, Wreg[0][kk], acc[0]);
                acc[1] = MFMA16(af, Wreg[1][kk], acc[1]);
                acc[2] = MFMA16(af, Wreg[2][kk], acc[2]);
                acc[3] = MFMA16(af, Wreg[3][kk], acc[3]);
            }
        }
        // ---- pointwise: gates are in-lane (acc[0..3] = i,f,g,o) ----
        unsigned short hbv[4];
        #pragma unroll
        for (int r = 0; r < 4; r++) {
            float ig = sigm(acc[0][r]);
            float fg = sigm(acc[1][r]);
            float gv = tanh_(acc[2][r]);
            float og = sigm(acc[3][r]);
            cst[r] = fg * cst[r] + ig * gv;
            hbv[r] = f2b(og * tanh_(cst[r]));
        }
        // publish: ring first (latency-critical)
        #pragma unroll
        for (int r = 0; r < 4; r++) {
            const int b = b0 + q * 4 + r;
            __hip_atomic_store(&ring[(t & 1) * 65536 + b * 512 + hid],
                               ((unsigned)t << 16) | hbv[r], __ATOMIC_RELAXED,
                               __HIP_MEMORY_SCOPE_AGENT);
        }
        // h_all: agent-visible packed 4B atomic stores (pair hid, hid^1)
        // so shadow helpers' LLC-direct atomic loads always see fresh data.
        #pragma unroll
        for (int r = 0; r < 4; r++) {
            const int b = b0 + q * 4 + r;
            int o = __shfl_xor((int)hbv[r], 1);
            if (!(l15 & 1)) {
                unsigned v = (unsigned)hbv[r] | (((unsigned)(unsigned short)o) << 16);
                __hip_atomic_store(
                    (unsigned*)&h_all[(long long)b * 262144 + (long long)t * 512 + hid],
                    v, __ATOMIC_RELAXED, __HIP_MEMORY_SCOPE_AGENT);
            }
        }
        // progress word every 16 steps: barrier drains all waves' h stores
        // (agent-visible), so prog >= t+1 implies h[..t] readable by helpers.
        if ((t & 15) == 15) {
            __syncthreads();
            if (tid == 0)
                __hip_atomic_store(&syncp[16 + (int)blockIdx.x * 16], t + 1,
                                   __ATOMIC_RELAXED, __HIP_MEMORY_SCOPE_AGENT);
        }
    }
}

// ---------------------------------------------------------------------------
// attn_out: e = Ve.tanh(a + u1b) (a from xg slots), softmax over T,
// context = alpha.h, head -> mu, sigma. 1 WG per b.
// ---------------------------------------------------------------------------
__global__ __launch_bounds__(256) void attn_out(
    const unsigned short* __restrict__ a_xg,  // fp32 a[] in xg slot layout
    const unsigned short* __restrict__ h_all,
    const unsigned short* __restrict__ u1bv,  // bf16 (128,512)
    const float* __restrict__ Ve,
    const float* __restrict__ Wout, const float* __restrict__ bout,
    float* __restrict__ outp)
{
    __shared__ float se[512];
    __shared__ float sm[512];
    __shared__ float red[8];
    const int b = blockIdx.x, tid = threadIdx.x;
    const int wv = tid >> 6, lane = tid & 63;

    // ---- phase 1: e[t] = sum_n Ve[n] * tanh(a[t,n] + u1b[b,n]) ----
    const int n0 = lane * 8;
    float ve[8], ub[8];
    #pragma unroll
    for (int j = 0; j < 8; j++) {
        ve[j] = Ve[n0 + j];
        ub[j] = b2f(u1bv[b * 512 + n0 + j]);
    }
    for (int it = 0; it < 64; it++) {
        const int t = it * 8 + wv * 2;
        const float* s0p = (const float*)
            &a_xg[(((long long)t * 32 + (n0 >> 5)) * 128 + b) * 64];
        const float* s1p = (const float*)
            &a_xg[(((long long)(t + 1) * 32 + (n0 >> 5)) * 128 + b) * 64];
        float4 a0 = *(const float4*)&s0p[n0 & 31];
        float4 a1 = *(const float4*)&s0p[(n0 & 31) + 4];
        float4 a2 = *(const float4*)&s1p[n0 & 31];
        float4 a3 = *(const float4*)&s1p[(n0 & 31) + 4];
        float s0 = ve[0] * tanh_(a0.x + ub[0]) + ve[1] * tanh_(a0.y + ub[1])
                 + ve[2] * tanh_(a0.z + ub[2]) + ve[3] * tanh_(a0.w + ub[3])
                 + ve[4] * tanh_(a1.x + ub[4]) + ve[5] * tanh_(a1.y + ub[5])
                 + ve[6] * tanh_(a1.z + ub[6]) + ve[7] * tanh_(a1.w + ub[7]);
        float s1 = ve[0] * tanh_(a2.x + ub[0]) + ve[1] * tanh_(a2.y + ub[1])
                 + ve[2] * tanh_(a2.z + ub[2]) + ve[3] * tanh_(a2.w + ub[3])
                 + ve[4] * tanh_(a3.x + ub[4]) + ve[5] * tanh_(a3.y + ub[5])
                 + ve[6] * tanh_(a3.z + ub[6]) + ve[7] * tanh_(a3.w + ub[7]);
        #pragma unroll
        for (int off = 1; off <= 32; off <<= 1) {
            s0 += __shfl_xor(s0, off);
            s1 += __shfl_xor(s1, off);
        }
        if (lane == 0) { se[t] = s0; se[t + 1] = s1; }
    }
    __syncthreads();

    // ---- phase 2: softmax over T ----
    float e0 = se[tid], e1 = se[256 + tid];
    float mx = fmaxf(e0, e1);
    for (int off = 32; off; off >>= 1) mx = fmaxf(mx, __shfl_xor(mx, off));
    if (lane == 0) red[wv] = mx;
    __syncthreads();
    mx = fmaxf(fmaxf(red[0], red[1]), fmaxf(red[2], red[3]));

    float s0 = __expf(e0 - mx), s1 = __expf(e1 - mx);
    sm[tid] = s0; sm[256 + tid] = s1;
    float ss = s0 + s1;
    for (int off = 32; off; off >>= 1) ss += __shfl_xor(ss, off);
    if (lane == 0) red[4 + wv] = ss;
    __syncthreads();
    float inv = 1.0f / (red[4] + red[5] + red[6] + red[7]);

    // ---- phase 3: context = alpha.h, head ----
    const unsigned int* hp = (const unsigned int*)(h_all + (long long)b * 262144);
    float a0 = 0.f, a1 = 0.f;
    for (int t = 0; t < 512; t += 4) {
        #pragma unroll
        for (int j = 0; j < 4; j++) {
            float al = sm[t + j];
            unsigned v = hp[(t + j) * 256 + tid];
            a0 += al * b2f((unsigned short)(v & 0xFFFFu));
            a1 += al * b2f((unsigned short)(v >> 16));
        }
    }
    a0 *= inv; a1 *= inv;

    float q0 = a0 * Wout[2 * tid] + a1 * Wout[2 * tid + 1];
    float q1 = a0 * Wout[512 + 2 * tid] + a1 * Wout[512 + 2 * tid + 1];
    for (int off = 32; off; off >>= 1) { q0 += __shfl_xor(q0, off); q1 += __shfl_xor(q1, off); }
    __syncthreads();  // red reuse
    if (lane == 0) { red[wv] = q0; red[4 + wv] = q1; }
    __syncthreads();
    if (tid == 0) {
        float P0 = red[0] + red[1] + red[2] + red[3] + bout[0];
        float P1 = red[4] + red[5] + red[6] + red[7] + bout[1];
        outp[b] = P0;
        float sp = (P1 > 15.0f) ? P1 : log1pf(__expf(P1));
        outp[128 + b] = sp + 1e-5f;
    }
}

// ---------------------------------------------------------------------------
extern "C" void kernel_launch(void* const* d_in, const int* in_sizes, int n_in,
                              void* d_out, int out_size, void* d_ws, size_t ws_size,
                              hipStream_t stream)
{
    const float* x    = (const float*)d_in[0];
    const float* Wih  = (const float*)d_in[1];
    const float* Whh  = (const float*)d_in[2];
    const float* bih  = (const float*)d_in[3];
    const float* bhh  = (const float*)d_in[4];
    const float* Ve   = (const float*)d_in[5];
    const float* U1   = (const float*)d_in[6];
    const float* U2   = (const float*)d_in[7];
    const float* Wout = (const float*)d_in[8];
    const float* bout = (const float*)d_in[9];
    float* out = (float*)d_out;

    char* ws = (char*)d_ws;
    size_t off = 0;
    auto alloc = [&](size_t bytes) -> void* {
        void* p = ws + off;
        off += (bytes + 255) & ~(size_t)255;
        return p;
    };
    unsigned short* x_bf   = (unsigned short*)alloc(33554432ull * 2);
    unsigned short* Wih_bf = (unsigned short*)alloc(1048576ull * 2);
    unsigned short* Whh_bf = (unsigned short*)alloc(1048576ull * 2);
    unsigned short* U1a    = (unsigned short*)alloc(262144ull * 2);
    unsigned short* U1b    = (unsigned short*)alloc(262144ull * 2);
    unsigned short* U2b    = (unsigned short*)alloc(262144ull * 2);
    float*          bias   = (float*)alloc(2048ull * 4);
    unsigned short* xg     = (unsigned short*)alloc(134217728ull * 2);
    unsigned short* h_all  = (unsigned short*)alloc(33554432ull * 2);
    unsigned short* u1bv   = (unsigned short*)alloc(65536ull * 2);
    unsigned int*   ring   = (unsigned int*)alloc(131072ull * 4);  // 2x128x512 tagged
    int*            syncp  = (int*)alloc(8192ull);  // [0]=gemm done; [16+wg*16]=prog
    if (off > ws_size) return;  // workspace too small: fail safe (no corruption)

    hipMemsetAsync(syncp, 0, 8192, stream);
    prep<<<4096, 256, 0, stream>>>(x, Wih, Whh, bih, bhh, U1, U2,
                                   x_bf, Wih_bf, Whh_bf, U1a, U1b, U2b, bias);
    // xg for t<128 only (ti=0): m0 = b*512, 2048 WGs
    gemm_bt<<<dim3(128, 16), 256, 0, stream>>>(x_bf, 512, Wih_bf, 512,
                                               xg, 2048, bias, 1, 512);
    // mega: 64 lstm + 6144 xg-gemm (t in [128,512)) + 2048 attn helpers
    mega<<<64 + GEMM_WGS + ATTN_WGS, 256, 0, stream>>>(
        xg, Whh_bf, h_all, ring, x_bf, Wih_bf, bias, xg, syncp, U1a, U2b);
    // u1b = h_last @ U1b^T
    gemm_bt<<<dim3(1, 4), 256, 0, stream>>>(h_all + 511 * 512, 262144, U1b, 512,
                                            u1bv, 512, nullptr, 0, 128);
    attn_out<<<128, 256, 0, stream>>>(xg, h_all, u1bv, Ve, Wout, bout, out);
}